// Round 14
// baseline (185.580 us; speedup 1.0000x reference)
//
#include <hip/hip_runtime.h>
#include <math.h>

static constexpr int N_NODES = 100000;
static constexpr int N_EDGES = 3200000;
static constexpr int F_INC   = 256;
static constexpr int HIDC    = 16;
static constexpr int NCLS    = 32;

static constexpr int BNODES  = 256;
static constexpr int NBKT    = (N_NODES + BNODES - 1) / BNODES;  // 391
static constexpr int CAP     = 9216;
static constexpr int CHUNK   = 4096;
static constexpr int NCHUNK  = (N_EDGES + CHUNK - 1) / CHUNK;    // 782
static constexpr int NTILES  = N_NODES / 16;                     // 6250
static constexpr int GLIN1   = (NTILES + 3) / 4;                 // 1563

typedef __attribute__((ext_vector_type(8))) short bf16x8;
typedef __attribute__((ext_vector_type(4))) float f32x4;

__device__ __forceinline__ unsigned pack_bf2(float a, float b) {
    unsigned ua = __float_as_uint(a);
    unsigned ub = __float_as_uint(b);
    ua = (ua + 0x7FFFu + ((ua >> 16) & 1u)) >> 16;
    ub = (ub + 0x7FFFu + ((ub >> 16) & 1u)) & 0xFFFF0000u;
    return ua | ub;
}
__device__ __forceinline__ float bflo(unsigned v) { return __uint_as_float(v << 16); }
__device__ __forceinline__ float bfhi(unsigned v) { return __uint_as_float(v & 0xFFFF0000u); }
__device__ __forceinline__ float elu1(float t) { return t > 0.f ? t : expm1f(t); }

__global__ void k_zero_cur(int* gcur) {
    int i = threadIdx.x;
    if (i < NBKT) gcur[i] = 0;
}

// Fused: blocks [0, NCHUNK) bucket edges; blocks [NCHUNK, ...) do MFMA linear1.
// The two paths are data-independent (linear1 stores UNSCALED bf16 h1).
__global__ __launch_bounds__(256) void k_bucklin(const int* __restrict__ src,
                                                 const int* __restrict__ dst,
                                                 int* gcur, unsigned int* __restrict__ slab,
                                                 const float* __restrict__ x,
                                                 const float* __restrict__ W1,
                                                 unsigned* __restrict__ hb) {
    __shared__ int sm[8192];   // 32 KB, overlaid per path
    int tid = threadIdx.x;
    if (blockIdx.x < NCHUNK) {
        // ---------------- bucket path ----------------
        int* hist  = sm;               // 512
        int* sc    = sm + 512;         // 512
        int* place = sm + 1024;        // 512
        int* gbase = sm + 1536;        // 512
        unsigned* staging = (unsigned*)(sm + 2048);        // 4096
        unsigned short* bid = (unsigned short*)(sm + 6144); // 4096 shorts
        int e0 = blockIdx.x * CHUNK;
        int n = min(CHUNK, N_EDGES - e0);
        hist[tid] = 0; hist[tid + 256] = 0;
        __syncthreads();
        unsigned pay[16];
        int bk[16];
        #pragma unroll
        for (int r = 0; r < 16; ++r) {
            int i = r * 256 + tid;
            bk[r] = -1;
            if (i < n) {
                int e = e0 + i;
                int s = src[e];
                int t = dst[e];
                int b = t >> 8;
                pay[r] = (unsigned)s | ((unsigned)(t & 255) << 24);
                bk[r] = b;
                atomicAdd(&hist[b], 1);
            }
        }
        __syncthreads();
        sc[tid] = hist[tid]; sc[tid + 256] = hist[tid + 256];
        __syncthreads();
        for (int off = 1; off < 512; off <<= 1) {
            int i0 = tid, i1 = tid + 256;
            int v0 = (i0 >= off) ? sc[i0 - off] : 0;
            int v1 = (i1 >= off) ? sc[i1 - off] : 0;
            __syncthreads();
            sc[i0] += v0; sc[i1] += v1;
            __syncthreads();
        }
        {
            int b0 = tid, b1 = tid + 256;
            int o0 = sc[b0] - hist[b0];
            int o1 = sc[b1] - hist[b1];
            place[b0] = o0; place[b1] = o1;
            sc[b0] = o0; sc[b1] = o1;
            if (b0 < NBKT && hist[b0]) gbase[b0] = atomicAdd(&gcur[b0], hist[b0]);
            if (b1 < NBKT && hist[b1]) gbase[b1] = atomicAdd(&gcur[b1], hist[b1]);
        }
        __syncthreads();
        #pragma unroll
        for (int r = 0; r < 16; ++r) {
            if (bk[r] >= 0) {
                int p = atomicAdd(&place[bk[r]], 1);
                staging[p] = pay[r];
                bid[p] = (unsigned short)bk[r];
            }
        }
        __syncthreads();
        for (int i = tid; i < n; i += 256) {
            int b = bid[i];
            int gp = gbase[b] + (i - sc[b]);
            if (gp < CAP) slab[(size_t)b * CAP + gp] = staging[i];
        }
    } else {
        // ---------------- MFMA linear1 path (unscaled bf16 h1) ----------------
        float* dtile = (float*)sm;     // [4][16][18]
        int lane = tid & 63;
        int w = tid >> 6;
        int tile = (blockIdx.x - NCHUNK) * 4 + w;
        if (tile >= NTILES) return;
        int g = lane >> 4;
        int r = lane & 15;
        union { uint4 u; bf16x8 v; } bfr[8];
        #pragma unroll
        for (int m = 0; m < 8; ++m) {
            unsigned uu[4];
            #pragma unroll
            for (int t = 0; t < 4; ++t) {
                int k0 = 32 * m + 8 * g + 2 * t;
                uu[t] = pack_bf2(W1[k0 * HIDC + r], W1[(k0 + 1) * HIDC + r]);
            }
            bfr[m].u = make_uint4(uu[0], uu[1], uu[2], uu[3]);
        }
        const float* xrow = x + (size_t)(tile * 16 + r) * F_INC;
        f32x4 acc = {0.f, 0.f, 0.f, 0.f};
        #pragma unroll
        for (int m = 0; m < 8; ++m) {
            int ks = 32 * m + 8 * g;
            float4 va = *(const float4*)(xrow + ks);
            float4 vb = *(const float4*)(xrow + ks + 4);
            union { uint4 u; bf16x8 v; } af;
            af.u = make_uint4(pack_bf2(va.x, va.y), pack_bf2(va.z, va.w),
                              pack_bf2(vb.x, vb.y), pack_bf2(vb.z, vb.w));
            acc = __builtin_amdgcn_mfma_f32_16x16x32_bf16(af.v, bfr[m].v, acc, 0, 0, 0);
        }
        float* dt = dtile + w * 288;   // 16*18
        #pragma unroll
        for (int t = 0; t < 4; ++t) dt[(4 * g + t) * 18 + r] = acc[t];
        __builtin_amdgcn_s_waitcnt(0);
        int q = lane & 7;
        #pragma unroll
        for (int h = 0; h < 2; ++h) {
            int rr = (lane >> 3) + 8 * h;
            int node = tile * 16 + rr;
            hb[(size_t)node * 8 + q] = pack_bf2(dt[rr * 18 + 2 * q], dt[rr * 18 + 2 * q + 1]);
        }
    }
}

// Per bucket: histogram local dst, scan, reorder in LDS, write back in place.
__global__ __launch_bounds__(512) void k_csr(const int* __restrict__ gcur,
                                             unsigned int* __restrict__ slab,
                                             int* __restrict__ rowptr,
                                             int* __restrict__ cnt,
                                             float* __restrict__ dis) {
    __shared__ int hist[BNODES];
    __shared__ int lofs[BNODES];
    __shared__ int place[BNODES];
    __shared__ unsigned int reord[CAP];
    int tid = threadIdx.x, b = blockIdx.x;
    if (tid < BNODES) hist[tid] = 0;
    __syncthreads();
    int count = min(gcur[b], CAP);
    unsigned int* sl = slab + (size_t)b * CAP;
    for (int i = tid; i < count; i += 512) atomicAdd(&hist[sl[i] >> 24], 1);
    __syncthreads();
    if (tid < BNODES) lofs[tid] = hist[tid];
    __syncthreads();
    for (int off = 1; off < BNODES; off <<= 1) {
        int v = 0;
        if (tid < BNODES && tid >= off) v = lofs[tid - off];
        __syncthreads();
        if (tid < BNODES) lofs[tid] += v;
        __syncthreads();
    }
    if (tid < BNODES) {
        int ex = lofs[tid] - hist[tid];
        lofs[tid] = ex;
        place[tid] = ex;
        int node = b * BNODES + tid;
        if (node < N_NODES) {
            rowptr[node] = b * CAP + ex;
            cnt[node] = hist[tid];
            dis[node] = rsqrtf((float)hist[tid] + 1.0f);
        }
    }
    __syncthreads();
    for (int i = tid; i < count; i += 512) {
        unsigned int v = sl[i];
        int dl = v >> 24;
        int p = atomicAdd(&place[dl], 1);
        reord[p] = v & 0xFFFFFFu;
    }
    __syncthreads();
    for (int i = tid; i < count; i += 512) sl[i] = reord[i];
}

// 4-lane/node gather core over a PRE-SCALED table (entry = dis[s]*h[s]).
__device__ __forceinline__ void gather4(int base, int deg, int q,
                                        const unsigned* __restrict__ csr,
                                        const unsigned* __restrict__ hb,
                                        float& a0, float& a1, float& a2, float& a3) {
    int j = 0;
    for (; j + 3 < deg; j += 4) {
        int s0 = csr[base + j];
        int s1 = csr[base + j + 1];
        int s2 = csr[base + j + 2];
        int s3 = csr[base + j + 3];
        uint2 v0 = *(const uint2*)&hb[(size_t)s0 * 8 + 2 * q];
        uint2 v1 = *(const uint2*)&hb[(size_t)s1 * 8 + 2 * q];
        uint2 v2 = *(const uint2*)&hb[(size_t)s2 * 8 + 2 * q];
        uint2 v3 = *(const uint2*)&hb[(size_t)s3 * 8 + 2 * q];
        a0 += (bflo(v0.x) + bflo(v1.x)) + (bflo(v2.x) + bflo(v3.x));
        a1 += (bfhi(v0.x) + bfhi(v1.x)) + (bfhi(v2.x) + bfhi(v3.x));
        a2 += (bflo(v0.y) + bflo(v1.y)) + (bflo(v2.y) + bflo(v3.y));
        a3 += (bfhi(v0.y) + bfhi(v1.y)) + (bfhi(v2.y) + bfhi(v3.y));
    }
    for (; j < deg; ++j) {
        int s = csr[base + j];
        uint2 v = *(const uint2*)&hb[(size_t)s * 8 + 2 * q];
        a0 += bflo(v.x); a1 += bfhi(v.x); a2 += bflo(v.y); a3 += bfhi(v.y);
    }
}

// Layer-1 gather over UNSCALED h1 table (per-edge dis[s]) + bias+ELU+@W2 -> prescaled table.
__global__ __launch_bounds__(256) void k_gather_fl1(const int* __restrict__ rowptr,
                                                    const int* __restrict__ cnt,
                                                    const unsigned* __restrict__ csr,
                                                    const float* __restrict__ dis,
                                                    const unsigned* __restrict__ hb,
                                                    const float* __restrict__ b1,
                                                    const float* __restrict__ W2,
                                                    unsigned* __restrict__ hb_out) {
    __shared__ float W2s[HIDC * HIDC];
    __shared__ float b1s[HIDC];
    if (threadIdx.x < HIDC * HIDC) W2s[threadIdx.x] = W2[threadIdx.x];
    if (threadIdx.x < HIDC) b1s[threadIdx.x] = b1[threadIdx.x];
    __syncthreads();
    int idx = blockIdx.x * blockDim.x + threadIdx.x;
    int n = idx >> 2;
    if (n >= N_NODES) return;
    int q = idx & 3;
    int lane = threadIdx.x & 63;
    int base = rowptr[n];
    int deg = cnt[n];
    float dn = dis[n];
    uint2 sv = *(const uint2*)&hb[(size_t)n * 8 + 2 * q];
    float a0 = dn * bflo(sv.x), a1 = dn * bfhi(sv.x);
    float a2 = dn * bflo(sv.y), a3 = dn * bfhi(sv.y);
    int j = 0;
    for (; j + 3 < deg; j += 4) {
        int s0 = csr[base + j];
        int s1 = csr[base + j + 1];
        int s2 = csr[base + j + 2];
        int s3 = csr[base + j + 3];
        float d0 = dis[s0], d1 = dis[s1], d2 = dis[s2], d3 = dis[s3];
        uint2 v0 = *(const uint2*)&hb[(size_t)s0 * 8 + 2 * q];
        uint2 v1 = *(const uint2*)&hb[(size_t)s1 * 8 + 2 * q];
        uint2 v2 = *(const uint2*)&hb[(size_t)s2 * 8 + 2 * q];
        uint2 v3 = *(const uint2*)&hb[(size_t)s3 * 8 + 2 * q];
        a0 += d0 * bflo(v0.x) + d1 * bflo(v1.x) + d2 * bflo(v2.x) + d3 * bflo(v3.x);
        a1 += d0 * bfhi(v0.x) + d1 * bfhi(v1.x) + d2 * bfhi(v2.x) + d3 * bfhi(v3.x);
        a2 += d0 * bflo(v0.y) + d1 * bflo(v1.y) + d2 * bflo(v2.y) + d3 * bflo(v3.y);
        a3 += d0 * bfhi(v0.y) + d1 * bfhi(v1.y) + d2 * bfhi(v2.y) + d3 * bfhi(v3.y);
    }
    for (; j < deg; ++j) {
        int s = csr[base + j];
        float ds = dis[s];
        uint2 v = *(const uint2*)&hb[(size_t)s * 8 + 2 * q];
        a0 += ds * bflo(v.x); a1 += ds * bfhi(v.x);
        a2 += ds * bflo(v.y); a3 += ds * bfhi(v.y);
    }
    a0 = elu1(dn * a0 + b1s[4 * q + 0]);
    a1 = elu1(dn * a1 + b1s[4 * q + 1]);
    a2 = elu1(dn * a2 + b1s[4 * q + 2]);
    a3 = elu1(dn * a3 + b1s[4 * q + 3]);
    // 4-lane shuffle matmul: h2[j] = sum_k act[k]*W2[k][j], j in [4q, 4q+4)
    int gb = lane & 60;
    float h0 = 0.f, h1 = 0.f, h2 = 0.f, h3 = 0.f;
    #pragma unroll
    for (int kl = 0; kl < 4; ++kl) {
        float e0 = __shfl(a0, gb + kl, 64);
        float e1 = __shfl(a1, gb + kl, 64);
        float e2 = __shfl(a2, gb + kl, 64);
        float e3 = __shfl(a3, gb + kl, 64);
        const float* w0 = &W2s[(4 * kl) * HIDC + 4 * q];
        const float* w1 = &W2s[(4 * kl + 1) * HIDC + 4 * q];
        const float* w2 = &W2s[(4 * kl + 2) * HIDC + 4 * q];
        const float* w3 = &W2s[(4 * kl + 3) * HIDC + 4 * q];
        h0 += e0 * w0[0] + e1 * w1[0] + e2 * w2[0] + e3 * w3[0];
        h1 += e0 * w0[1] + e1 * w1[1] + e2 * w2[1] + e3 * w3[1];
        h2 += e0 * w0[2] + e1 * w1[2] + e2 * w2[2] + e3 * w3[2];
        h3 += e0 * w0[3] + e1 * w1[3] + e2 * w2[3] + e3 * w3[3];
    }
    *(uint2*)&hb_out[(size_t)n * 8 + 2 * q] =
        make_uint2(pack_bf2(dn * h0, dn * h1), pack_bf2(dn * h2, dn * h3));
}

// Layer-2 gather (prescaled table): z2 = elu(agg + b2) -> prescaled table.
__global__ __launch_bounds__(256) void k_gather_z(const int* __restrict__ rowptr,
                                                  const int* __restrict__ cnt,
                                                  const unsigned* __restrict__ csr,
                                                  const float* __restrict__ dis,
                                                  const unsigned* __restrict__ hb,
                                                  const float* __restrict__ bias,
                                                  unsigned* __restrict__ outp) {
    int idx = blockIdx.x * blockDim.x + threadIdx.x;
    int n = idx >> 2;
    if (n >= N_NODES) return;
    int q = idx & 3;
    uint2 sv = *(const uint2*)&hb[(size_t)n * 8 + 2 * q];
    float a0 = bflo(sv.x), a1 = bfhi(sv.x), a2 = bflo(sv.y), a3 = bfhi(sv.y);
    gather4(rowptr[n], cnt[n], q, csr, hb, a0, a1, a2, a3);
    float dn = dis[n];
    float z0 = elu1(a0 * dn + bias[4 * q + 0]);
    float z1 = elu1(a1 * dn + bias[4 * q + 1]);
    float z2 = elu1(a2 * dn + bias[4 * q + 2]);
    float z3 = elu1(a3 * dn + bias[4 * q + 3]);
    *(uint2*)&outp[(size_t)n * 8 + 2 * q] =
        make_uint2(pack_bf2(dn * z0, dn * z1), pack_bf2(dn * z2, dn * z3));
}

// Layer-3 gather + @W3 + b3 + ELU + log_softmax. Lane q -> classes [8q, 8q+8).
__global__ __launch_bounds__(256) void k_gather_fin(const int* __restrict__ rowptr,
                                                    const int* __restrict__ cnt,
                                                    const unsigned* __restrict__ csr,
                                                    const float* __restrict__ dis,
                                                    const unsigned* __restrict__ hb,
                                                    const float* __restrict__ W3,
                                                    const float* __restrict__ b3,
                                                    float* __restrict__ out) {
    __shared__ float W3s[HIDC * NCLS];
    __shared__ float b3s[NCLS];
    for (int i = threadIdx.x; i < HIDC * NCLS; i += 256) W3s[i] = W3[i];
    if (threadIdx.x < NCLS) b3s[threadIdx.x] = b3[threadIdx.x];
    __syncthreads();
    int idx = blockIdx.x * blockDim.x + threadIdx.x;
    int n = idx >> 2;
    if (n >= N_NODES) return;
    int q = idx & 3;
    int lane = threadIdx.x & 63;
    uint2 sv = *(const uint2*)&hb[(size_t)n * 8 + 2 * q];
    float a0 = bflo(sv.x), a1 = bfhi(sv.x), a2 = bflo(sv.y), a3 = bfhi(sv.y);
    gather4(rowptr[n], cnt[n], q, csr, hb, a0, a1, a2, a3);
    float dn = dis[n];
    a0 *= dn; a1 *= dn; a2 *= dn; a3 *= dn;     // g[4q .. 4q+3]
    int gb = lane & 60;
    int j0 = q * 8;
    float r[8];
    #pragma unroll
    for (int c = 0; c < 8; ++c) r[c] = b3s[j0 + c];
    #pragma unroll
    for (int kl = 0; kl < 4; ++kl) {
        float e0 = __shfl(a0, gb + kl, 64);
        float e1 = __shfl(a1, gb + kl, 64);
        float e2 = __shfl(a2, gb + kl, 64);
        float e3 = __shfl(a3, gb + kl, 64);
        const float* w0 = &W3s[(4 * kl) * NCLS + j0];
        const float* w1 = &W3s[(4 * kl + 1) * NCLS + j0];
        const float* w2 = &W3s[(4 * kl + 2) * NCLS + j0];
        const float* w3 = &W3s[(4 * kl + 3) * NCLS + j0];
        #pragma unroll
        for (int c = 0; c < 8; ++c)
            r[c] += e0 * w0[c] + e1 * w1[c] + e2 * w2[c] + e3 * w3[c];
    }
    float m = -1e30f;
    #pragma unroll
    for (int c = 0; c < 8; ++c) { r[c] = elu1(r[c]); m = fmaxf(m, r[c]); }
    m = fmaxf(m, __shfl_xor(m, 1, 64));
    m = fmaxf(m, __shfl_xor(m, 2, 64));
    float s = 0.f;
    #pragma unroll
    for (int c = 0; c < 8; ++c) s += expf(r[c] - m);
    s += __shfl_xor(s, 1, 64);
    s += __shfl_xor(s, 2, 64);
    float lse = logf(s) + m;
    float4* o = (float4*)(out + (size_t)n * NCLS + j0);
    o[0] = make_float4(r[0] - lse, r[1] - lse, r[2] - lse, r[3] - lse);
    o[1] = make_float4(r[4] - lse, r[5] - lse, r[6] - lse, r[7] - lse);
}

extern "C" void kernel_launch(void* const* d_in, const int* in_sizes, int n_in,
                              void* d_out, int out_size, void* d_ws, size_t ws_size,
                              hipStream_t stream) {
    const float* x  = (const float*)d_in[0];
    const int*   ei = (const int*)d_in[1];
    const float* W1 = (const float*)d_in[2];
    const float* b1 = (const float*)d_in[3];
    const float* W2 = (const float*)d_in[4];
    const float* b2 = (const float*)d_in[5];
    const float* W3 = (const float*)d_in[6];
    const float* b3 = (const float*)d_in[7];
    float* out = (float*)d_out;
    const int* src = ei;
    const int* dst = ei + N_EDGES;

    int* wi = (int*)d_ws;
    int*          gcur   = wi;                                   // 512
    unsigned int* slab   = (unsigned int*)(wi + 512);            // NBKT*CAP
    int*          rowptr = wi + 512 + NBKT * CAP;                // 102,400
    int*          cnt    = rowptr + 102400;                      // 102,400
    float*        dis    = (float*)(cnt + 102400);               // 102,400
    unsigned*     Bh     = (unsigned*)(dis + 102400);            // 819,200
    unsigned*     Zb     = Bh + 819200;                          // 819,200
    (void)ws_size; (void)n_in; (void)in_sizes; (void)out_size;

    const int GG4 = (int)(((long long)N_NODES * 4 + 255) / 256);   // 1563

    k_zero_cur<<<1, 512, 0, stream>>>(gcur);
    // bucket (782 blocks) || MFMA linear1 (1563 blocks) in ONE launch
    k_bucklin<<<NCHUNK + GLIN1, 256, 0, stream>>>(src, dst, gcur, slab, x, W1, Bh);
    k_csr<<<NBKT, 512, 0, stream>>>(gcur, slab, rowptr, cnt, dis);

    // Layer 1: gather over unscaled h1 (per-edge dis) + bias+ELU+@W2 -> Zb
    k_gather_fl1<<<GG4, 256, 0, stream>>>(rowptr, cnt, slab, dis, Bh, b1, W2, Zb);
    // Layer 2: gather -> z2 = elu(agg+b2) -> Bh
    k_gather_z<<<GG4, 256, 0, stream>>>(rowptr, cnt, slab, dis, Zb, b2, Bh);
    // Layer 3: gather -> @W3+b3 -> ELU -> log_softmax -> out
    k_gather_fin<<<GG4, 256, 0, stream>>>(rowptr, cnt, slab, dis, Bh, W3, b3, out);
}

// Round 15
// 175.720 us; speedup vs baseline: 1.0561x; 1.0561x over previous
//
#include <hip/hip_runtime.h>
#include <math.h>

static constexpr int N_NODES = 100000;
static constexpr int N_EDGES = 3200000;
static constexpr int F_INC   = 256;
static constexpr int HIDC    = 16;
static constexpr int NCLS    = 32;

static constexpr int BNODES  = 256;
static constexpr int NBKT    = (N_NODES + BNODES - 1) / BNODES;  // 391
static constexpr int CAP     = 9216;
static constexpr int CHUNK   = 4096;
static constexpr int NCHUNK  = (N_EDGES + CHUNK - 1) / CHUNK;    // 782
static constexpr int NTILES  = N_NODES / 16;                     // 6250
static constexpr int GLIN1   = (NTILES + 3) / 4;                 // 1563

typedef __attribute__((ext_vector_type(8))) short bf16x8;
typedef __attribute__((ext_vector_type(4))) float f32x4;

__device__ __forceinline__ unsigned pack_bf2(float a, float b) {
    unsigned ua = __float_as_uint(a);
    unsigned ub = __float_as_uint(b);
    ua = (ua + 0x7FFFu + ((ua >> 16) & 1u)) >> 16;
    ub = (ub + 0x7FFFu + ((ub >> 16) & 1u)) & 0xFFFF0000u;
    return ua | ub;
}
__device__ __forceinline__ float bflo(unsigned v) { return __uint_as_float(v << 16); }
__device__ __forceinline__ float bfhi(unsigned v) { return __uint_as_float(v & 0xFFFF0000u); }
__device__ __forceinline__ float elu1(float t) { return t > 0.f ? t : expm1f(t); }

__global__ void k_zero_cur(int* gcur) {
    int i = threadIdx.x;
    if (i < NBKT) gcur[i] = 0;
}

// Bin a chunk of 4096 edges by dst bucket in LDS, flush bucket-sorted runs to the slab.
__global__ __launch_bounds__(256) void k_bucket(const int* __restrict__ src,
                                                const int* __restrict__ dst,
                                                int* gcur, unsigned int* __restrict__ slab) {
    __shared__ int hist[512];
    __shared__ int sc[512];
    __shared__ int place[512];
    __shared__ int gbase[512];
    __shared__ unsigned int staging[CHUNK];
    __shared__ unsigned short bid[CHUNK];
    int tid = threadIdx.x;
    int e0 = blockIdx.x * CHUNK;
    int n = min(CHUNK, N_EDGES - e0);
    hist[tid] = 0; hist[tid + 256] = 0;
    __syncthreads();
    unsigned int pay[16];
    int bk[16];
    #pragma unroll
    for (int r = 0; r < 16; ++r) {
        int i = r * 256 + tid;
        bk[r] = -1;
        if (i < n) {
            int e = e0 + i;
            int s = src[e];
            int t = dst[e];
            int b = t >> 8;
            pay[r] = (unsigned)s | ((unsigned)(t & 255) << 24);
            bk[r] = b;
            atomicAdd(&hist[b], 1);
        }
    }
    __syncthreads();
    sc[tid] = hist[tid]; sc[tid + 256] = hist[tid + 256];
    __syncthreads();
    for (int off = 1; off < 512; off <<= 1) {
        int i0 = tid, i1 = tid + 256;
        int v0 = (i0 >= off) ? sc[i0 - off] : 0;
        int v1 = (i1 >= off) ? sc[i1 - off] : 0;
        __syncthreads();
        sc[i0] += v0; sc[i1] += v1;
        __syncthreads();
    }
    {
        int b0 = tid, b1 = tid + 256;
        int o0 = sc[b0] - hist[b0];
        int o1 = sc[b1] - hist[b1];
        place[b0] = o0; place[b1] = o1;
        sc[b0] = o0; sc[b1] = o1;
        if (b0 < NBKT && hist[b0]) gbase[b0] = atomicAdd(&gcur[b0], hist[b0]);
        if (b1 < NBKT && hist[b1]) gbase[b1] = atomicAdd(&gcur[b1], hist[b1]);
    }
    __syncthreads();
    #pragma unroll
    for (int r = 0; r < 16; ++r) {
        if (bk[r] >= 0) {
            int p = atomicAdd(&place[bk[r]], 1);
            staging[p] = pay[r];
            bid[p] = (unsigned short)bk[r];
        }
    }
    __syncthreads();
    for (int i = tid; i < n; i += 256) {
        int b = bid[i];
        int gp = gbase[b] + (i - sc[b]);
        if (gp < CAP) slab[(size_t)b * CAP + gp] = staging[i];
    }
}

// Per bucket: histogram local dst, scan, reorder in LDS, write back in place.
__global__ __launch_bounds__(512) void k_csr(const int* __restrict__ gcur,
                                             unsigned int* __restrict__ slab,
                                             int* __restrict__ rowptr,
                                             int* __restrict__ cnt,
                                             float* __restrict__ dis) {
    __shared__ int hist[BNODES];
    __shared__ int lofs[BNODES];
    __shared__ int place[BNODES];
    __shared__ unsigned int reord[CAP];
    int tid = threadIdx.x, b = blockIdx.x;
    if (tid < BNODES) hist[tid] = 0;
    __syncthreads();
    int count = min(gcur[b], CAP);
    unsigned int* sl = slab + (size_t)b * CAP;
    for (int i = tid; i < count; i += 512) atomicAdd(&hist[sl[i] >> 24], 1);
    __syncthreads();
    if (tid < BNODES) lofs[tid] = hist[tid];
    __syncthreads();
    for (int off = 1; off < BNODES; off <<= 1) {
        int v = 0;
        if (tid < BNODES && tid >= off) v = lofs[tid - off];
        __syncthreads();
        if (tid < BNODES) lofs[tid] += v;
        __syncthreads();
    }
    if (tid < BNODES) {
        int ex = lofs[tid] - hist[tid];
        lofs[tid] = ex;
        place[tid] = ex;
        int node = b * BNODES + tid;
        if (node < N_NODES) {
            rowptr[node] = b * CAP + ex;
            cnt[node] = hist[tid];
            dis[node] = rsqrtf((float)hist[tid] + 1.0f);
        }
    }
    __syncthreads();
    for (int i = tid; i < count; i += 512) {
        unsigned int v = sl[i];
        int dl = v >> 24;
        int p = atomicAdd(&place[dl], 1);
        reord[p] = v & 0xFFFFFFu;
    }
    __syncthreads();
    for (int i = tid; i < count; i += 512) sl[i] = reord[i];
}

// h1 = x @ W1 via MFMA, pre-scaled by dis[n], packed bf16. (R13-proven.)
__global__ __launch_bounds__(256) void k_linear1(const float* __restrict__ x,
                                                 const float* __restrict__ W1,
                                                 const float* __restrict__ dis,
                                                 unsigned* __restrict__ hb) {
    __shared__ float dtile[4][16][18];
    int tid = threadIdx.x;
    int lane = tid & 63;
    int w = tid >> 6;
    int tile = blockIdx.x * 4 + w;
    if (tile >= NTILES) return;
    int g = lane >> 4;
    int r = lane & 15;
    union { uint4 u; bf16x8 v; } bfr[8];
    #pragma unroll
    for (int m = 0; m < 8; ++m) {
        unsigned uu[4];
        #pragma unroll
        for (int t = 0; t < 4; ++t) {
            int k0 = 32 * m + 8 * g + 2 * t;
            uu[t] = pack_bf2(W1[k0 * HIDC + r], W1[(k0 + 1) * HIDC + r]);
        }
        bfr[m].u = make_uint4(uu[0], uu[1], uu[2], uu[3]);
    }
    const float* xrow = x + (size_t)(tile * 16 + r) * F_INC;
    f32x4 acc = {0.f, 0.f, 0.f, 0.f};
    #pragma unroll
    for (int m = 0; m < 8; ++m) {
        int ks = 32 * m + 8 * g;
        float4 va = *(const float4*)(xrow + ks);
        float4 vb = *(const float4*)(xrow + ks + 4);
        union { uint4 u; bf16x8 v; } af;
        af.u = make_uint4(pack_bf2(va.x, va.y), pack_bf2(va.z, va.w),
                          pack_bf2(vb.x, vb.y), pack_bf2(vb.z, vb.w));
        acc = __builtin_amdgcn_mfma_f32_16x16x32_bf16(af.v, bfr[m].v, acc, 0, 0, 0);
    }
    #pragma unroll
    for (int t = 0; t < 4; ++t) dtile[w][4 * g + t][r] = acc[t];
    __builtin_amdgcn_s_waitcnt(0);
    int q = lane & 7;
    #pragma unroll
    for (int h = 0; h < 2; ++h) {
        int rr = (lane >> 3) + 8 * h;
        int node = tile * 16 + rr;
        float dn = dis[node];
        hb[(size_t)node * 8 + q] =
            pack_bf2(dn * dtile[w][rr][2 * q], dn * dtile[w][rr][2 * q + 1]);
    }
}

// 4-lane/node gather core over a PRE-SCALED table (entry = dis[s]*h[s]).
__device__ __forceinline__ void gather4(int base, int deg, int q,
                                        const unsigned* __restrict__ csr,
                                        const unsigned* __restrict__ hb,
                                        float& a0, float& a1, float& a2, float& a3) {
    int j = 0;
    for (; j + 3 < deg; j += 4) {
        int s0 = csr[base + j];
        int s1 = csr[base + j + 1];
        int s2 = csr[base + j + 2];
        int s3 = csr[base + j + 3];
        uint2 v0 = *(const uint2*)&hb[(size_t)s0 * 8 + 2 * q];
        uint2 v1 = *(const uint2*)&hb[(size_t)s1 * 8 + 2 * q];
        uint2 v2 = *(const uint2*)&hb[(size_t)s2 * 8 + 2 * q];
        uint2 v3 = *(const uint2*)&hb[(size_t)s3 * 8 + 2 * q];
        a0 += (bflo(v0.x) + bflo(v1.x)) + (bflo(v2.x) + bflo(v3.x));
        a1 += (bfhi(v0.x) + bfhi(v1.x)) + (bfhi(v2.x) + bfhi(v3.x));
        a2 += (bflo(v0.y) + bflo(v1.y)) + (bflo(v2.y) + bflo(v3.y));
        a3 += (bfhi(v0.y) + bfhi(v1.y)) + (bfhi(v2.y) + bfhi(v3.y));
    }
    for (; j < deg; ++j) {
        int s = csr[base + j];
        uint2 v = *(const uint2*)&hb[(size_t)s * 8 + 2 * q];
        a0 += bflo(v.x); a1 += bfhi(v.x); a2 += bflo(v.y); a3 += bfhi(v.y);
    }
}

// Layer-1 gather (prescaled table) + bias+ELU+@W2 -> prescaled table.
__global__ __launch_bounds__(256) void k_gather_fl1(const int* __restrict__ rowptr,
                                                    const int* __restrict__ cnt,
                                                    const unsigned* __restrict__ csr,
                                                    const float* __restrict__ dis,
                                                    const unsigned* __restrict__ hb,
                                                    const float* __restrict__ b1,
                                                    const float* __restrict__ W2,
                                                    unsigned* __restrict__ hb_out) {
    __shared__ float W2s[HIDC * HIDC];
    __shared__ float b1s[HIDC];
    if (threadIdx.x < HIDC * HIDC) W2s[threadIdx.x] = W2[threadIdx.x];
    if (threadIdx.x < HIDC) b1s[threadIdx.x] = b1[threadIdx.x];
    __syncthreads();
    int idx = blockIdx.x * blockDim.x + threadIdx.x;
    int n = idx >> 2;
    if (n >= N_NODES) return;
    int q = idx & 3;
    int lane = threadIdx.x & 63;
    uint2 sv = *(const uint2*)&hb[(size_t)n * 8 + 2 * q];
    float a0 = bflo(sv.x), a1 = bfhi(sv.x), a2 = bflo(sv.y), a3 = bfhi(sv.y);
    gather4(rowptr[n], cnt[n], q, csr, hb, a0, a1, a2, a3);
    float dn = dis[n];
    a0 = elu1(a0 * dn + b1s[4 * q + 0]);
    a1 = elu1(a1 * dn + b1s[4 * q + 1]);
    a2 = elu1(a2 * dn + b1s[4 * q + 2]);
    a3 = elu1(a3 * dn + b1s[4 * q + 3]);
    int gb = lane & 60;
    float h0 = 0.f, h1 = 0.f, h2 = 0.f, h3 = 0.f;
    #pragma unroll
    for (int kl = 0; kl < 4; ++kl) {
        float e0 = __shfl(a0, gb + kl, 64);
        float e1 = __shfl(a1, gb + kl, 64);
        float e2 = __shfl(a2, gb + kl, 64);
        float e3 = __shfl(a3, gb + kl, 64);
        const float* w0 = &W2s[(4 * kl) * HIDC + 4 * q];
        const float* w1 = &W2s[(4 * kl + 1) * HIDC + 4 * q];
        const float* w2 = &W2s[(4 * kl + 2) * HIDC + 4 * q];
        const float* w3 = &W2s[(4 * kl + 3) * HIDC + 4 * q];
        h0 += e0 * w0[0] + e1 * w1[0] + e2 * w2[0] + e3 * w3[0];
        h1 += e0 * w0[1] + e1 * w1[1] + e2 * w2[1] + e3 * w3[1];
        h2 += e0 * w0[2] + e1 * w1[2] + e2 * w2[2] + e3 * w3[2];
        h3 += e0 * w0[3] + e1 * w1[3] + e2 * w2[3] + e3 * w3[3];
    }
    *(uint2*)&hb_out[(size_t)n * 8 + 2 * q] =
        make_uint2(pack_bf2(dn * h0, dn * h1), pack_bf2(dn * h2, dn * h3));
}

// Layer-2 gather (prescaled table): z2 = elu(agg + b2) -> prescaled table.
__global__ __launch_bounds__(256) void k_gather_z(const int* __restrict__ rowptr,
                                                  const int* __restrict__ cnt,
                                                  const unsigned* __restrict__ csr,
                                                  const float* __restrict__ dis,
                                                  const unsigned* __restrict__ hb,
                                                  const float* __restrict__ bias,
                                                  unsigned* __restrict__ outp) {
    int idx = blockIdx.x * blockDim.x + threadIdx.x;
    int n = idx >> 2;
    if (n >= N_NODES) return;
    int q = idx & 3;
    uint2 sv = *(const uint2*)&hb[(size_t)n * 8 + 2 * q];
    float a0 = bflo(sv.x), a1 = bfhi(sv.x), a2 = bflo(sv.y), a3 = bfhi(sv.y);
    gather4(rowptr[n], cnt[n], q, csr, hb, a0, a1, a2, a3);
    float dn = dis[n];
    float z0 = elu1(a0 * dn + bias[4 * q + 0]);
    float z1 = elu1(a1 * dn + bias[4 * q + 1]);
    float z2 = elu1(a2 * dn + bias[4 * q + 2]);
    float z3 = elu1(a3 * dn + bias[4 * q + 3]);
    *(uint2*)&outp[(size_t)n * 8 + 2 * q] =
        make_uint2(pack_bf2(dn * z0, dn * z1), pack_bf2(dn * z2, dn * z3));
}

// Layer-3 gather + @W3 + b3 + ELU + log_softmax. Lane q -> classes [8q, 8q+8).
__global__ __launch_bounds__(256) void k_gather_fin(const int* __restrict__ rowptr,
                                                    const int* __restrict__ cnt,
                                                    const unsigned* __restrict__ csr,
                                                    const float* __restrict__ dis,
                                                    const unsigned* __restrict__ hb,
                                                    const float* __restrict__ W3,
                                                    const float* __restrict__ b3,
                                                    float* __restrict__ out) {
    __shared__ float W3s[HIDC * NCLS];
    __shared__ float b3s[NCLS];
    for (int i = threadIdx.x; i < HIDC * NCLS; i += 256) W3s[i] = W3[i];
    if (threadIdx.x < NCLS) b3s[threadIdx.x] = b3[threadIdx.x];
    __syncthreads();
    int idx = blockIdx.x * blockDim.x + threadIdx.x;
    int n = idx >> 2;
    if (n >= N_NODES) return;
    int q = idx & 3;
    int lane = threadIdx.x & 63;
    uint2 sv = *(const uint2*)&hb[(size_t)n * 8 + 2 * q];
    float a0 = bflo(sv.x), a1 = bfhi(sv.x), a2 = bflo(sv.y), a3 = bfhi(sv.y);
    gather4(rowptr[n], cnt[n], q, csr, hb, a0, a1, a2, a3);
    float dn = dis[n];
    a0 *= dn; a1 *= dn; a2 *= dn; a3 *= dn;
    int gb = lane & 60;
    int j0 = q * 8;
    float r[8];
    #pragma unroll
    for (int c = 0; c < 8; ++c) r[c] = b3s[j0 + c];
    #pragma unroll
    for (int kl = 0; kl < 4; ++kl) {
        float e0 = __shfl(a0, gb + kl, 64);
        float e1 = __shfl(a1, gb + kl, 64);
        float e2 = __shfl(a2, gb + kl, 64);
        float e3 = __shfl(a3, gb + kl, 64);
        const float* w0 = &W3s[(4 * kl) * NCLS + j0];
        const float* w1 = &W3s[(4 * kl + 1) * NCLS + j0];
        const float* w2 = &W3s[(4 * kl + 2) * NCLS + j0];
        const float* w3 = &W3s[(4 * kl + 3) * NCLS + j0];
        #pragma unroll
        for (int c = 0; c < 8; ++c)
            r[c] += e0 * w0[c] + e1 * w1[c] + e2 * w2[c] + e3 * w3[c];
    }
    float m = -1e30f;
    #pragma unroll
    for (int c = 0; c < 8; ++c) { r[c] = elu1(r[c]); m = fmaxf(m, r[c]); }
    m = fmaxf(m, __shfl_xor(m, 1, 64));
    m = fmaxf(m, __shfl_xor(m, 2, 64));
    float s = 0.f;
    #pragma unroll
    for (int c = 0; c < 8; ++c) s += expf(r[c] - m);
    s += __shfl_xor(s, 1, 64);
    s += __shfl_xor(s, 2, 64);
    float lse = logf(s) + m;
    float4* o = (float4*)(out + (size_t)n * NCLS + j0);
    o[0] = make_float4(r[0] - lse, r[1] - lse, r[2] - lse, r[3] - lse);
    o[1] = make_float4(r[4] - lse, r[5] - lse, r[6] - lse, r[7] - lse);
}

extern "C" void kernel_launch(void* const* d_in, const int* in_sizes, int n_in,
                              void* d_out, int out_size, void* d_ws, size_t ws_size,
                              hipStream_t stream) {
    const float* x  = (const float*)d_in[0];
    const int*   ei = (const int*)d_in[1];
    const float* W1 = (const float*)d_in[2];
    const float* b1 = (const float*)d_in[3];
    const float* W2 = (const float*)d_in[4];
    const float* b2 = (const float*)d_in[5];
    const float* W3 = (const float*)d_in[6];
    const float* b3 = (const float*)d_in[7];
    float* out = (float*)d_out;
    const int* src = ei;
    const int* dst = ei + N_EDGES;

    int* wi = (int*)d_ws;
    int*          gcur   = wi;                                   // 512
    unsigned int* slab   = (unsigned int*)(wi + 512);            // NBKT*CAP
    int*          rowptr = wi + 512 + NBKT * CAP;                // 102,400
    int*          cnt    = rowptr + 102400;                      // 102,400
    float*        dis    = (float*)(cnt + 102400);               // 102,400
    unsigned*     Bh     = (unsigned*)(dis + 102400);            // 819,200
    unsigned*     Zb     = Bh + 819200;                          // 819,200
    (void)ws_size; (void)n_in; (void)in_sizes; (void)out_size;

    const int GG4 = (int)(((long long)N_NODES * 4 + 255) / 256);   // 1563

    k_zero_cur<<<1, 512, 0, stream>>>(gcur);
    k_bucket<<<NCHUNK, 256, 0, stream>>>(src, dst, gcur, slab);
    k_csr<<<NBKT, 512, 0, stream>>>(gcur, slab, rowptr, cnt, dis);

    // Layer 1: h1 = x@W1 via MFMA (pre-scaled bf16) -> gather+bias+ELU+@W2 -> Zb
    k_linear1<<<GLIN1, 256, 0, stream>>>(x, W1, dis, Bh);
    k_gather_fl1<<<GG4, 256, 0, stream>>>(rowptr, cnt, slab, dis, Bh, b1, W2, Zb);
    // Layer 2: gather -> z2 = elu(agg+b2) -> Bh
    k_gather_z<<<GG4, 256, 0, stream>>>(rowptr, cnt, slab, dis, Zb, b2, Bh);
    // Layer 3: gather -> @W3+b3 -> ELU -> log_softmax -> out
    k_gather_fin<<<GG4, 256, 0, stream>>>(rowptr, cnt, slab, dis, Bh, W3, b3, out);
}